// Round 9
// baseline (149.542 us; speedup 1.0000x reference)
//
#include <hip/hip_runtime.h>
#include <hip/hip_bf16.h>
#include <math.h>

// ChamferLoss: pred [32,4096,3] f32, gt [32,4096,3] f32 -> scalar f32.
//
// d2(q,t) = p2 + (t2 - 2 q.t); min over t folds only (t2 - 2 q.t); p2 and
// sqrt once per query. Inner: 3 v_fma + 1/2 v_min3 per pair = 3.5 insts
// x 2 cyc -> issue floor 47.8 us on 1024 SIMDs.
//
// R8 post-mortem: VALUBusy 99% at 2.1x the floor. The compiler SLP-packs
// paired scalar fmaf (d0/d1) into v_pk_fma_f32, which issues at 8 cyc
// (half FLOP rate). Evidence: R7 = 128x416x4 cyc = 88.7us (measured 92),
// R8 = 256x416x2 = 88.7us (measured 102 incl. fused epilogue). R9: inner
// loop in inline asm (v_fma_f32 chain + v_min3_f32) -- opaque to SLP, so
// the 2-cyc scalar path is guaranteed. Launch config and fused finish kept
// from R8 (waves_per_eu(2,2), grid 512, TCH=512, atomicMin merge,
// completion-counter finishers, single memset init).

#define TPB   256
#define QPT   16            // all 4096 queries of (dir,b) per block
#define NPTS  4096
#define TSPL  8
#define TCH   (NPTS / TSPL) // 512 targets per block (8 KB LDS)
#define NQTOT (2 * 32 * NPTS)

// ws layout (uints):
//   [0, NQTOT)       : mins[262144]   (init 0xFF; uint order == float order)
//   [NQTOT, +64)     : cnt[64]        (init 0xFF; wrap math handles it)
//   [NQTOT+64, +64)  : float partial[64] (overwritten by finishers)
//   [NQTOT+128]      : gcount         (init 0xFF)
#define WS_INIT ((NQTOT + 129) * 4)

// Opaque scalar FMA chain: d = qx*gx + (qy*gy + (qz*gz + gw)). SLP cannot
// pack across asm boundaries, guaranteeing 2-cyc v_fma_f32 (the 157TF path).
__device__ __forceinline__ float dist_fma(float qx, float qy, float qz,
                                          float gx, float gy, float gz,
                                          float gw) {
    float d;
    asm("v_fma_f32 %0, %1, %2, %3" : "=v"(d) : "v"(qz), "v"(gz), "v"(gw));
    asm("v_fma_f32 %0, %1, %2, %0" : "+v"(d) : "v"(qy), "v"(gy));
    asm("v_fma_f32 %0, %1, %2, %0" : "+v"(d) : "v"(qx), "v"(gx));
    return d;
}
__device__ __forceinline__ float min3(float a, float b, float c) {
    float d;
    asm("v_min3_f32 %0, %1, %2, %3" : "=v"(d) : "v"(a), "v"(b), "v"(c));
    return d;
}

__global__ __attribute__((amdgpu_flat_work_group_size(TPB, TPB)))
__attribute__((amdgpu_waves_per_eu(2, 2)))
void chamfer_fused(const float* __restrict__ pred,
                   const float* __restrict__ gt,
                   unsigned int* __restrict__ ws,
                   float* __restrict__ out)
{
    // grid.x = 512: dir (2) x batch (32) x tsplit (8)
    const int bx  = blockIdx.x;
    const int dir = bx >> 8;
    const int rem = bx & 255;
    const int b   = rem >> 3;
    const int kt  = rem & 7;
    const int g   = dir * 32 + b;

    unsigned int* mins    = ws;
    unsigned int* cnt     = ws + NQTOT;
    float*        partial = (float*)(ws + NQTOT + 64);
    unsigned int* gcount  = ws + NQTOT + 128;

    const float* __restrict__ qbase = (dir ? gt : pred) + (size_t)b * NPTS * 3;
    const float* __restrict__ tbase = (dir ? pred : gt) + (size_t)b * NPTS * 3;

    __shared__ float4 sT[TCH];          // (-2x,-2y,-2z, t2)  8 KB
    __shared__ float swave[TPB / 64];
    __shared__ unsigned int sflag1, sflag2;

    const int tid = threadIdx.x;
    if (tid == 0) { sflag1 = 0u; sflag2 = 0u; }

    // Stage this block's 512-target slice: 2 points per thread
    for (int j = tid; j < TCH; j += TPB) {
        const float* tp = tbase + (size_t)(kt * TCH + j) * 3;
        float x = tp[0], y = tp[1], z = tp[2];
        sT[j] = make_float4(-2.0f * x, -2.0f * y, -2.0f * z,
                            fmaf(x, x, fmaf(y, y, z * z)));
    }

    // 16 queries per thread
    float qx[QPT], qy[QPT], qz[QPT], mn[QPT];
#pragma unroll
    for (int i = 0; i < QPT; ++i) {
        const float* q = qbase + (size_t)(i * TPB + tid) * 3;
        qx[i] = q[0]; qy[i] = q[1]; qz[i] = q[2];
        mn[i] = 1e30f;
    }

    __syncthreads();

    // 2 targets/iter: per query 6 v_fma + 1 v_min3 (all asm, un-packable)
    // -> 112 x 2cyc VALU insts per 2 ds_read_b128 (LDS pipe at 43%).
#pragma unroll 2
    for (int j = 0; j < TCH; j += 2) {
        const float4 g0 = sT[j];
        const float4 g1 = sT[j + 1];
#pragma unroll
        for (int i = 0; i < QPT; ++i) {
            float d0 = dist_fma(qx[i], qy[i], qz[i], g0.x, g0.y, g0.z, g0.w);
            float d1 = dist_fma(qx[i], qy[i], qz[i], g1.x, g1.y, g1.z, g1.w);
            mn[i] = min3(d0, d1, mn[i]);
        }
    }

    // Merge partial mins across the 8 tsplit siblings (d2 > 0 -> uint
    // bit-pattern order == float order; slots init 0xFFFFFFFF = uint max).
    unsigned int* wq = mins + (size_t)g * NPTS;
#pragma unroll
    for (int i = 0; i < QPT; ++i) {
        float p2 = fmaf(qx[i], qx[i], fmaf(qy[i], qy[i], qz[i] * qz[i]));
        float d2 = fmaxf(mn[i] + p2, 1e-12f);
        atomicMin(&wq[i * TPB + tid], __float_as_uint(d2));
    }

    // Group completion: 8th arriver (old == 0xFFFFFFFF + 7 = 6) finishes.
    __syncthreads();
    if (tid == 0) {
        __threadfence();
        unsigned int old = atomicAdd(&cnt[g], 1u);
        if (old == 6u) sflag1 = 1u;
    }
    __syncthreads();

    float s = 0.0f;
    if (sflag1) {
        // Finisher block: sqrt + sum its group's 4096 merged mins.
        // Atomic RMW reads resolve at the device coherence point.
#pragma unroll
        for (int r = 0; r < QPT; ++r) {
            unsigned int u = atomicAdd(&wq[r * TPB + tid], 0u);
            s += sqrtf(__uint_as_float(u));
        }
    }
#pragma unroll
    for (int off = 32; off > 0; off >>= 1)
        s += __shfl_down(s, off, 64);
    const int wid = tid >> 6, lane = tid & 63;
    if (lane == 0) swave[wid] = s;
    __syncthreads();
    if (tid == 0 && sflag1) {
        float tot = swave[0] + swave[1] + swave[2] + swave[3];
        atomicExch(&partial[g], tot);
        __threadfence();
        unsigned int o2 = atomicAdd(gcount, 1u);   // init 0xFFFFFFFF
        if (o2 == 62u) sflag2 = 1u;                // 64th (last) finisher
    }
    __syncthreads();
    if (sflag2 && tid < 64) {
        float v = atomicAdd(&partial[tid], 0.0f);
#pragma unroll
        for (int off = 32; off > 0; off >>= 1)
            v += __shfl_down(v, off, 64);
        if (tid == 0) out[0] = v * (1.0f / 131072.0f);
    }
}

extern "C" void kernel_launch(void* const* d_in, const int* in_sizes, int n_in,
                              void* d_out, int out_size, void* d_ws, size_t ws_size,
                              hipStream_t stream)
{
    const float* pred = (const float*)d_in[0];
    const float* gt   = (const float*)d_in[1];
    float* out        = (float*)d_out;
    unsigned int* ws  = (unsigned int*)d_ws;

    // One init: mins + counters to 0xFF (uint-max; counter wrap handled).
    hipMemsetAsync(d_ws, 0xFF, WS_INIT, stream);
    chamfer_fused<<<dim3(512), dim3(TPB), 0, stream>>>(pred, gt, ws, out);
}